// Round 5
// baseline (988.226 us; speedup 1.0000x reference)
//
#include <hip/hip_runtime.h>
#include <hip/hip_bf16.h>

// TransformerDecLayer on MI355X (gfx950).
// B=8, SQ=512, SK=1024, D=1024, H=16, DK=64, F=4096.
// GEMMs: bf16 MFMA 16x16x32, 128x128 tile, global_load_lds(16B) staging (m97 pattern).
// R4: launch-count 34 -> 13 (prep megakernel, co-launches, split-K + LN-fused reduce).
// R5: XCD swizzle for attention (K/V L2-resident per XCD: FETCH 135->21MB).
// R6: attention = R4's proven q64/3-ring/single-barrier schedule + R5's XCD swizzle
//     + clean 1-GLD16/thread staging (R4 double-staged) + plain P stores (R5's
//     nontemporal stores caused ~1.9x HBM write amplification: 498 vs 264 MB).
// Workspace (MB): 0 xb(8) | 8 encb(16) | 24 x1f(16) | 40 x2f(16) | 56 xcb(8)
//   64 wT(32) | 96 biases(1) | 104 QKV/Qc(24) | 128 KVc(32) | 160 VtSelf(8)
//   176 Ob(8) | 200 part(64) | 264 Asf(32, FFN hidden) | 332 VtCross(16)

using bf16 = __hip_bfloat16;
typedef __attribute__((ext_vector_type(8))) short short8;
typedef __attribute__((ext_vector_type(4))) float f32x4;

#define DEVINL __device__ __forceinline__

DEVINL unsigned short bf16bits(float f) {
  __hip_bfloat16 h = __float2bfloat16(f);
  return *reinterpret_cast<unsigned short*>(&h);
}
DEVINL float bits2f(unsigned short u) {
  return __uint_as_float(((unsigned int)u) << 16);
}
DEVINL float tofloat(float f) { return f; }
DEVINL float tofloat(bf16 h) { return __bfloat162float(h); }

#define GLD16(gp, lp) __builtin_amdgcn_global_load_lds( \
    (__attribute__((address_space(1))) const void*)(gp), \
    (__attribute__((address_space(3))) void*)(lp), 16, 0, 0)

struct GemmP {
  const bf16* A; const bf16* Bt; void* C;
  const float* bias; const int* kmask;
  float scale;
  int M, N, K, lda, ldb, ldc;
  long sAb, sAh, sBb, sBh, sCb, sCh;  // element strides: base = (z>>4)*sXb + (z&15)*sXh
};

enum { EPI_BIAS_BF16 = 0, EPI_CAUSAL_BF16, EPI_KMASK_F32, EPI_NONE_BF16,
       EPI_BIAS_F32, EPI_BIAS_RELU_BF16, EPI_PART_F32 };

template<int EPI>
DEVINL void gemm_body(const GemmP& p, int bx, int by, int bz) {
  __shared__ bf16 As[128 * 32];
  __shared__ bf16 Bs[128 * 32];
  const int t = threadIdx.x;
  const int lane = t & 63;
  const int w = t >> 6;
  const int zb = bz >> 4, zh = bz & 15;
  const int m0 = by * 128, n0 = bx * 128;

  const bf16* Ab = p.A + (long)zb * p.sAb + (long)zh * p.sAh;
  const bf16* Bb = p.Bt + (long)zb * p.sBb + (long)zh * p.sBh;
  const int fl = lane & 15, fq = lane >> 4;
  const int wm = (w >> 1) * 64, wn = (w & 1) * 64;

  f32x4 acc[4][4];
#pragma unroll
  for (int i = 0; i < 4; ++i)
#pragma unroll
    for (int j = 0; j < 4; ++j) acc[i][j] = (f32x4){0.f, 0.f, 0.f, 0.f};

  const int sr = t >> 2;          // staging row 0..63
  const int sc = (t & 3) * 8;     // staging col (bf16 elems)
  char* ldsA = (char*)As + w * 1024;
  char* ldsB = (char*)Bs + w * 1024;

  int brow0 = n0 + sr;      if (brow0 > p.N - 1) brow0 = p.N - 1;
  int brow1 = n0 + sr + 64; if (brow1 > p.N - 1) brow1 = p.N - 1;

  for (int k0 = 0; k0 < p.K; k0 += 32) {
    GLD16(Ab + (long)(m0 + sr) * p.lda + k0 + sc, ldsA);
    GLD16(Ab + (long)(m0 + sr + 64) * p.lda + k0 + sc, ldsA + 4096);
    GLD16(Bb + (long)brow0 * p.ldb + k0 + sc, ldsB);
    GLD16(Bb + (long)brow1 * p.ldb + k0 + sc, ldsB + 4096);
    __syncthreads();

    short8 af[4], bfv[4];
#pragma unroll
    for (int i = 0; i < 4; ++i)
      af[i] = *(const short8*)(As + (wm + i * 16 + fl) * 32 + fq * 8);
#pragma unroll
    for (int j = 0; j < 4; ++j)
      bfv[j] = *(const short8*)(Bs + (wn + j * 16 + fl) * 32 + fq * 8);
#pragma unroll
    for (int i = 0; i < 4; ++i)
#pragma unroll
      for (int j = 0; j < 4; ++j)
        acc[i][j] = __builtin_amdgcn_mfma_f32_16x16x32_bf16(af[i], bfv[j], acc[i][j], 0, 0, 0);
    __syncthreads();
  }

  const float NEGINF = -__builtin_inff();
  const long cbase = (long)zb * p.sCb + (long)zh * p.sCh;
#pragma unroll
  for (int i = 0; i < 4; ++i) {
#pragma unroll
    for (int j = 0; j < 4; ++j) {
#pragma unroll
      for (int r = 0; r < 4; ++r) {
        int row = m0 + wm + i * 16 + fq * 4 + r;
        int col = n0 + wn + j * 16 + fl;
        if (col < p.N) {
          float v = acc[i][j][r];
          if (EPI == EPI_BIAS_BF16 || EPI == EPI_BIAS_F32 || EPI == EPI_BIAS_RELU_BF16)
            v += p.bias[col];
          if (EPI == EPI_BIAS_RELU_BF16) v = v > 0.f ? v : 0.f;
          if (EPI == EPI_CAUSAL_BF16) { v *= p.scale; if (col > row) v = NEGINF; }
          if (EPI == EPI_KMASK_F32)   { v *= p.scale; if (p.kmask[zb * 1024 + col] == 0) v = NEGINF; }
          long off = cbase + (long)row * p.ldc + col;
          if (EPI == EPI_KMASK_F32 || EPI == EPI_BIAS_F32 || EPI == EPI_PART_F32)
            ((float*)p.C)[off] = v;
          else ((bf16*)p.C)[off] = __float2bfloat16(v);
        }
      }
    }
  }
}

template<int EPI>
__global__ __launch_bounds__(256)
void gemm_k(GemmP p) {
  gemm_body<EPI>(p, blockIdx.x, blockIdx.y, blockIdx.z);
}

// two independent EPI_BIAS_BF16 gemms in one launch (linear block decode)
struct Gemm2P { GemmP a, b; int nA, axw, bxw; };
__global__ __launch_bounds__(256)
void gemm2_k(Gemm2P q) {
  const int b = blockIdx.x;
  if (b < q.nA) gemm_body<EPI_BIAS_BF16>(q.a, b % q.axw, b / q.axw, 0);
  else { const int c = b - q.nA; gemm_body<EPI_BIAS_BF16>(q.b, c % q.bxw, c / q.bxw, 0); }
}

// ---------------- fused attention v4 (R4 schedule + XCD swizzle) ----------------
// One block = 64 q-rows of one (b,h). 8 waves (512 threads).
// S[64][SK] bf16 in LDS, byte-swizzled (^(row&7)<<4): conflict-free short8 row access.
// K then V streamed as [64][64] bf16 tiles, 3-buffer GLD16 ring, 1 GLD16/thread/tile,
// counted vmcnt(1), ONE barrier per tile (stage(kt+2) targets the buffer whose readers
// all passed the previous barrier). Grid 1024 linear; bijective XCD swizzle gives each
// XCD 16 consecutive (b,h) -> K/V (~4MB) stays in that XCD's L2.
struct AttnP {
  const bf16 *Q, *K, *Vt;
  float* Pout; bf16* O;
  const int* kmask;
  int ldq, ldk, ldv;
  long sQb, sQh, sKb, sKh, sVb, sVh, sPb, sPh, sOb, sOh;
};

template<int SK, bool CAUSAL, bool WRITE_P>
__global__ __launch_bounds__(512)
void attn_fused_k(AttnP p) {
  constexpr int TKMAX = SK / 64;
  __shared__ bf16 S[64 * SK];        // swizzled bf16 scores -> probs
  __shared__ bf16 ring[3 * 4096];    // 3 x 8KB [64][64] tiles
  const int t = threadIdx.x;
  const int lane = t & 63;
  const int w = t >> 6;              // 0..7
  const int fl = lane & 15, fq = lane >> 4;
  const int qh = w >> 2;             // q 32-row half
  const int wc = w & 3;              // 16-col quarter
  // bijective XCD swizzle over 1024 blocks: XCD gets 128 consecutive wg
  // = 16 (b,h) x 8 q-blocks -> K/V stays in that XCD's L2.
  const int lin = blockIdx.x;
  const int wg = (lin & 7) * 128 + (lin >> 3);
  const int by = wg & 7;
  const int z = wg >> 3;
  const int zb = z >> 4, zh = z & 15;
  const int q0 = by * 64;
  const float NEGINF = -__builtin_inff();

  const bf16* Qb = p.Q + (long)zb * p.sQb + (long)zh * p.sQh;
  const bf16* Kb = p.K + (long)zb * p.sKb + (long)zh * p.sKh;
  const bf16* Vb = p.Vt + (long)zb * p.sVb + (long)zh * p.sVh;

  const int Tk = CAUSAL ? (q0 >> 6) + 1 : TKMAX;   // causal: only tiles touching diag

  // Q fragments straight from global (L2-resident)
  short8 af[2][2];
#pragma unroll
  for (int i = 0; i < 2; ++i)
#pragma unroll
    for (int kk = 0; kk < 2; ++kk)
      af[i][kk] = *(const short8*)(Qb + (long)(q0 + qh * 32 + i * 16 + fl) * p.ldq + kk * 32 + fq * 8);

  int kmv[CAUSAL ? 1 : TKMAX];
  if (!CAUSAL) {
#pragma unroll
    for (int kt = 0; kt < TKMAX; ++kt)
      kmv[kt] = p.kmask[zb * 1024 + kt * 64 + wc * 16 + fl];
  }

  // 1 GLD16/thread per tile (512 x 16B = 8KB tile exactly).
  // LDS dest: wave-uniform base (HW adds lane*16); global src inverse-swizzled.
  const int so = t * 16;
  const int srow = so >> 7;
  const int scb = (so & 127) ^ ((srow & 7) << 4);
  auto stage = [&](const bf16* mb, int ld, int roff, int coff, int buf) {
    GLD16(mb + (long)(roff + srow) * ld + coff + (scb >> 1),
          (char*)ring + buf * 8192 + w * 1024);
  };

  // ---- phase 1: S = Q K^T * scale (+mask), bf16 into LDS ----
  // invariant: at iter kt's wait, outstanding stages are {kt, kt+1}; vmcnt(1)
  // drains kt. stage(kt+2) targets buf (kt-1)%3 whose readers passed barrier kt.
  stage(Kb, p.ldk, 0, 0, 0);
  if (Tk > 1) stage(Kb, p.ldk, 64, 0, 1);
  for (int kt = 0; kt < Tk; ++kt) {
    if (kt + 1 < Tk) asm volatile("s_waitcnt vmcnt(1)" ::: "memory");
    else             asm volatile("s_waitcnt vmcnt(0)" ::: "memory");
    __builtin_amdgcn_s_barrier();
    if (kt + 2 < Tk) stage(Kb, p.ldk, (kt + 2) * 64, 0, (kt + 2) % 3);

    const char* kb = (const char*)ring + (kt % 3) * 8192;
    const int krow = wc * 16 + fl;
    short8 bfv[2];
#pragma unroll
    for (int kk = 0; kk < 2; ++kk)
      bfv[kk] = *(const short8*)(kb + ((krow * 128 + kk * 64 + fq * 16) ^ ((krow & 7) << 4)));
    f32x4 acc[2] = {(f32x4){0.f,0.f,0.f,0.f}, (f32x4){0.f,0.f,0.f,0.f}};
#pragma unroll
    for (int kk = 0; kk < 2; ++kk) {
      acc[0] = __builtin_amdgcn_mfma_f32_16x16x32_bf16(af[0][kk], bfv[kk], acc[0], 0, 0, 0);
      acc[1] = __builtin_amdgcn_mfma_f32_16x16x32_bf16(af[1][kk], bfv[kk], acc[1], 0, 0, 0);
    }
    const int col = kt * 64 + krow;
    const bool mok = CAUSAL || (kmv[CAUSAL ? 0 : kt] != 0);
#pragma unroll
    for (int i = 0; i < 2; ++i) {
#pragma unroll
      for (int r = 0; r < 4; ++r) {
        int row = qh * 32 + i * 16 + fq * 4 + r;
        float v = acc[i][r] * 0.125f;
        if (CAUSAL) { if (col > q0 + row) v = NEGINF; }
        else if (!mok) v = NEGINF;
        *(bf16*)((char*)S + (((row * SK + col) * 2) ^ ((row & 7) << 4))) = __float2bfloat16(v);
      }
    }
  }
  asm volatile("s_waitcnt lgkmcnt(0)" ::: "memory");
  __builtin_amdgcn_s_barrier();

  // ---- prefetch V under softmax ----
  const int Tv = Tk;
  stage(Vb, p.ldv, 0, 0, 0);
  if (Tv > 1) stage(Vb, p.ldv, 0, 64, 1);

  // ---- phase 2: softmax (wave w owns rows w*8..w*8+7); bf16 P to LDS, f32 P out ----
  float* Pf = WRITE_P ? (p.Pout + (long)zb * p.sPb + (long)zh * p.sPh) : nullptr;
  constexpr int NC = SK / 512;
  const int lim = Tk * 64;
  for (int rr = 0; rr < 8; ++rr) {
    const int row = w * 8 + rr;
    const int rg = q0 + row;
    const int swz = (row & 7) << 4;
    float fv[NC][8];
#pragma unroll
    for (int c = 0; c < NC; ++c) {
      const int col = c * 512 + lane * 8;
      if (!CAUSAL || col < lim) {
        short8 sv = *(const short8*)((char*)S + (((row * SK + col) * 2) ^ swz));
#pragma unroll
        for (int j = 0; j < 8; ++j) fv[c][j] = bits2f((unsigned short)sv[j]);
      } else {
#pragma unroll
        for (int j = 0; j < 8; ++j) fv[c][j] = NEGINF;
      }
    }
    float mx = fv[0][0];
#pragma unroll
    for (int c = 0; c < NC; ++c)
#pragma unroll
      for (int j = 0; j < 8; ++j) mx = fmaxf(mx, fv[c][j]);
    for (int off = 32; off; off >>= 1) mx = fmaxf(mx, __shfl_xor(mx, off, 64));
    float s = 0.f;
#pragma unroll
    for (int c = 0; c < NC; ++c)
#pragma unroll
      for (int j = 0; j < 8; ++j) { fv[c][j] = expf(fv[c][j] - mx); s += fv[c][j]; }
    for (int off = 32; off; off >>= 1) s += __shfl_xor(s, off, 64);
    const float inv = 1.f / s;
#pragma unroll
    for (int c = 0; c < NC; ++c) {
      const int col = c * 512 + lane * 8;
      if (!CAUSAL || col < lim) {
        short8 o;
#pragma unroll
        for (int j = 0; j < 8; ++j) o[j] = (short)bf16bits(fv[c][j] * inv);
        *(short8*)((char*)S + (((row * SK + col) * 2) ^ swz)) = o;
        if (WRITE_P) {
          float* pp = Pf + (long)rg * SK + col;
          f32x4 o0, o1;
#pragma unroll
          for (int j = 0; j < 4; ++j) { o0[j] = fv[c][j] * inv; o1[j] = fv[c][4 + j] * inv; }
          *(f32x4*)pp = o0;
          *(f32x4*)(pp + 4) = o1;
        }
      }
    }
  }
  asm volatile("s_waitcnt lgkmcnt(0)" ::: "memory");
  __builtin_amdgcn_s_barrier();

  // ---- phase 3: O = P V ; wave w: q-half qh, dk cols wc*16..+15 ----
  f32x4 ao[2] = {(f32x4){0.f,0.f,0.f,0.f}, (f32x4){0.f,0.f,0.f,0.f}};
  for (int vt = 0; vt < Tv; ++vt) {
    if (vt + 1 < Tv) asm volatile("s_waitcnt vmcnt(1)" ::: "memory");
    else             asm volatile("s_waitcnt vmcnt(0)" ::: "memory");
    __builtin_amdgcn_s_barrier();
    if (vt + 2 < Tv) stage(Vb, p.ldv, 0, (vt + 2) * 64, (vt + 2) % 3);

    const char* vbuf = (const char*)ring + (vt % 3) * 8192;
    const int vrow = wc * 16 + fl;
    short8 bv[2];
#pragma unroll
    for (int kk = 0; kk < 2; ++kk)
      bv[kk] = *(const short8*)(vbuf + ((vrow * 128 + kk * 64 + fq * 16) ^ ((vrow & 7) << 4)));
#pragma unroll
    for (int i = 0; i < 2; ++i) {
      const int row = qh * 32 + i * 16 + fl;
#pragma unroll
      for (int kk = 0; kk < 2; ++kk) {
        const int col = vt * 64 + kk * 32 + fq * 8;
        short8 pa = *(const short8*)((char*)S + (((row * SK + col) * 2) ^ ((row & 7) << 4)));
        ao[i] = __builtin_amdgcn_mfma_f32_16x16x32_bf16(pa, bv[kk], ao[i], 0, 0, 0);
      }
    }
  }

  bf16* Ob_ = p.O + (long)zb * p.sOb + (long)zh * p.sOh;
#pragma unroll
  for (int i = 0; i < 2; ++i)
#pragma unroll
    for (int r = 0; r < 4; ++r) {
      int row = q0 + qh * 32 + i * 16 + fq * 4 + r;
      Ob_[(long)row * 1024 + wc * 16 + fl] = __float2bfloat16(ao[i][r]);
    }
}

// out = LN(x + sum_{s<NP} part[s] + pbias); writes f32 outf and optional bf16 outb.
template<int NP>
__global__ __launch_bounds__(256)
void ln_fuse_k(const float* __restrict__ x, const float* __restrict__ part, long pstride,
               const float* __restrict__ pb,
               const float* __restrict__ g, const float* __restrict__ bt,
               float* __restrict__ outf, bf16* __restrict__ outb) {
  const int lane = threadIdx.x & 63;
  const long row = (long)blockIdx.x * 4 + (threadIdx.x >> 6);
  const float* px = x + row * 1024;
  float4 v[4];
  float s = 0.f;
#pragma unroll
  for (int c = 0; c < 4; ++c) {
    const int col = c * 256 + lane * 4;
    float4 a = *(const float4*)(px + col);
    float4 bb = *(const float4*)(pb + col);
    v[c].x = a.x + bb.x; v[c].y = a.y + bb.y; v[c].z = a.z + bb.z; v[c].w = a.w + bb.w;
#pragma unroll
    for (int sl = 0; sl < NP; ++sl) {
      float4 pp = *(const float4*)(part + sl * pstride + row * 1024 + col);
      v[c].x += pp.x; v[c].y += pp.y; v[c].z += pp.z; v[c].w += pp.w;
    }
    s += v[c].x + v[c].y + v[c].z + v[c].w;
  }
  for (int off = 32; off; off >>= 1) s += __shfl_xor(s, off, 64);
  float mu = s * (1.f / 1024.f);
  float q = 0.f;
#pragma unroll
  for (int c = 0; c < 4; ++c) {
    float dx = v[c].x - mu, dy = v[c].y - mu, dz = v[c].z - mu, dw = v[c].w - mu;
    q += dx * dx + dy * dy + dz * dz + dw * dw;
  }
  for (int off = 32; off; off >>= 1) q += __shfl_xor(q, off, 64);
  float rs = rsqrtf(q * (1.f / 1024.f) + 1e-5f);
#pragma unroll
  for (int c = 0; c < 4; ++c) {
    int col = c * 256 + lane * 4;
    float4 gg = *(const float4*)(g + col);
    float4 bb = *(const float4*)(bt + col);
    float4 o;
    o.x = (v[c].x - mu) * rs * gg.x + bb.x;
    o.y = (v[c].y - mu) * rs * gg.y + bb.y;
    o.z = (v[c].z - mu) * rs * gg.z + bb.z;
    o.w = (v[c].w - mu) * rs * gg.w + bb.w;
    *(float4*)(outf + row * 1024 + col) = o;
    if (outb) {
      uint2 pk;
      pk.x = bf16bits(o.x) | ((unsigned)bf16bits(o.y) << 16);
      pk.y = bf16bits(o.z) | ((unsigned)bf16bits(o.w) << 16);
      *(uint2*)(outb + row * 1024 + col) = pk;
    }
  }
}

// 32x32 transpose tile body (out[c*ldo+r] = bf16(in[r*ldi+c]))
template<typename TI>
DEVINL void tr_body(const TI* __restrict__ pin, bf16* __restrict__ pout,
                    int ldi, int ldo, int c0, int r0, int t, float tile[32][33]) {
  const int tx = t & 31, ty = t >> 5;  // 32x8
#pragma unroll
  for (int i = 0; i < 32; i += 8)
    tile[ty + i][tx] = tofloat(pin[(long)(r0 + ty + i) * ldi + c0 + tx]);
  __syncthreads();
#pragma unroll
  for (int i = 0; i < 32; i += 8)
    pout[(long)(c0 + ty + i) * ldo + r0 + tx] = __float2bfloat16(tile[tx][ty + i]);
}

// prep megakernel: cvt x, cvt enc, 8 square weight^T, ff_w1^T, ff_w2^T, bias concats.
struct PrepP {
  const float *x, *enc;
  const float* wsrc[10];
  const float *b0, *b1, *b2, *b4, *b5;
  bf16 *xb, *encb, *wT;
  float *bqkv, *bkv;
};
__global__ __launch_bounds__(256)
void prep_k(PrepP p) {
  __shared__ float tile[32][33];
  const int b = blockIdx.x, t = threadIdx.x;
  if (b < 12288) {
    const float* src = (b < 4096) ? p.x : p.enc;
    bf16* dst = (b < 4096) ? p.xb : p.encb;
    long i = (long)(b < 4096 ? b : b - 4096) * 256 + t;
    float4 v = *(const float4*)(src + i * 4);
    uint2 pk;
    pk.x = bf16bits(v.x) | ((unsigned)bf16bits(v.y) << 16);
    pk.y = bf16bits(v.z) | ((unsigned)bf16bits(v.w) << 16);
    *(uint2*)(dst + i * 4) = pk;
  } else if (b < 20480) {
    int l = b - 12288; int wdx = l >> 10; l &= 1023;
    tr_body<float>(p.wsrc[wdx], p.wT + (long)wdx * 1048576, 1024, 1024,
                   (l & 31) * 32, (l >> 5) * 32, t, tile);
  } else if (b < 24576) {
    int l = b - 20480;   // ff_w1 [1024][4096] -> [4096][1024]
    tr_body<float>(p.wsrc[8], p.wT + 8l * 1048576, 4096, 1024,
                   (l & 127) * 32, (l >> 7) * 32, t, tile);
  } else if (b < 28672) {
    int l = b - 24576;   // ff_w2 [4096][1024] -> [1024][4096]
    tr_body<float>(p.wsrc[9], p.wT + 12l * 1048576, 1024, 4096,
                   (l % 32) * 32, (l / 32) * 32, t, tile);
  } else if (b < 28684) {
    int i = (b - 28672) * 256 + t;
    p.bqkv[i] = (i < 1024) ? p.b0[i] : (i < 2048 ? p.b1[i - 1024] : p.b2[i - 2048]);
  } else {
    int i = (b - 28684) * 256 + t;
    p.bkv[i] = (i < 1024) ? p.b4[i] : p.b5[i - 1024];
  }
}

// both V transposes in one launch. [0,4096): self (z=128, 2x16 tiles); rest: cross (2x32).
struct Vt2P { const bf16 *vs, *vc; bf16 *vts, *vtc; };
__global__ __launch_bounds__(256)
void vt2_k(Vt2P p) {
  __shared__ float tile[32][33];
  const int b = blockIdx.x, t = threadIdx.x;
  if (b < 4096) {
    int z = b >> 5, l = b & 31;
    int zb = z >> 4, zh = z & 15;
    tr_body<bf16>(p.vs + (long)zb * 1572864 + zh * 64,
                  p.vts + (long)zb * 524288 + zh * 32768,
                  3072, 512, (l & 1) * 32, (l >> 1) * 32, t, tile);
  } else {
    int c = b - 4096;
    int z = c >> 6, l = c & 63;
    int zb = z >> 4, zh = z & 15;
    tr_body<bf16>(p.vc + (long)zb * 2097152 + zh * 64,
                  p.vtc + (long)zb * 1048576 + zh * 65536,
                  2048, 1024, (l & 1) * 32, (l >> 1) * 32, t, tile);
  }
}

static inline GemmP mkp(const void* A, const bf16* Bt, void* C,
                        const float* bias, const int* km, float sc,
                        int M, int N, int K, int lda, int ldb, int ldc,
                        long sAb, long sAh, long sBb, long sBh, long sCb, long sCh) {
  GemmP p;
  p.A = (const bf16*)A; p.Bt = Bt; p.C = C; p.bias = bias; p.kmask = km; p.scale = sc;
  p.M = M; p.N = N; p.K = K; p.lda = lda; p.ldb = ldb; p.ldc = ldc;
  p.sAb = sAb; p.sAh = sAh; p.sBb = sBb; p.sBh = sBh; p.sCb = sCb; p.sCh = sCh;
  return p;
}

extern "C" void kernel_launch(void* const* d_in, const int* in_sizes, int n_in,
                              void* d_out, int out_size, void* d_ws, size_t ws_size,
                              hipStream_t stream) {
  const float* x        = (const float*)d_in[0];
  const float* enc_o    = (const float*)d_in[1];
  const int*   enc_mask = (const int*)d_in[2];
  const float* a1_wq = (const float*)d_in[3];  const float* a1_bq = (const float*)d_in[4];
  const float* a1_wk = (const float*)d_in[5];  const float* a1_bk = (const float*)d_in[6];
  const float* a1_wv = (const float*)d_in[7];  const float* a1_bv = (const float*)d_in[8];
  const float* a1_wo = (const float*)d_in[9];  const float* a1_bo = (const float*)d_in[10];
  const float* a2_wq = (const float*)d_in[11]; const float* a2_bq = (const float*)d_in[12];
  const float* a2_wk = (const float*)d_in[13]; const float* a2_bk = (const float*)d_in[14];
  const float* a2_wv = (const float*)d_in[15]; const float* a2_bv = (const float*)d_in[16];
  const float* a2_wo = (const float*)d_in[17]; const float* a2_bo = (const float*)d_in[18];
  const float* ff_w1 = (const float*)d_in[19]; const float* ff_b1 = (const float*)d_in[20];
  const float* ff_w2 = (const float*)d_in[21]; const float* ff_b2 = (const float*)d_in[22];
  const float* ln1_g = (const float*)d_in[23]; const float* ln1_b = (const float*)d_in[24];
  const float* ln2_g = (const float*)d_in[25]; const float* ln2_b = (const float*)d_in[26];
  const float* ln3_g = (const float*)d_in[27]; const float* ln3_b = (const float*)d_in[28];

  const size_t MB = 1u << 20;
  const long M1 = 1048576;  // elements
  char* w = (char*)d_ws;
  bf16*  xb   = (bf16*)(w + 0);
  bf16*  encb = (bf16*)(w + 8 * MB);
  float* x1f  = (float*)(w + 24 * MB);
  float* x2f  = (float*)(w + 40 * MB);
  bf16*  xcb  = (bf16*)(w + 56 * MB);
  bf16*  wT   = (bf16*)(w + 64 * MB);   // 16M elems = 32MB
  float* bqkv = (float*)(w + 96 * MB);  // [3072]
  float* bkv  = (float*)(w + 96 * MB + 16384);  // [2048]
  bf16*  QKV  = (bf16*)(w + 104 * MB);  // self: [4096,3072]; cross: Qc [4096,1024]
  bf16*  KVc  = (bf16*)(w + 128 * MB);  // cross: [8192,2048]
  bf16*  VtS  = (bf16*)(w + 160 * MB);  // self V^T [B,H,64,512] 8MB
  bf16*  Ob   = (bf16*)(w + 176 * MB);
  float* part = (float*)(w + 200 * MB); // 4 x [4096,1024] f32
  bf16*  Asf  = (bf16*)(w + 264 * MB);  // FFN hidden 32MB
  bf16*  VtC  = (bf16*)(w + 332 * MB);  // cross V^T [B,H,64,1024] 16MB

  float* out_x = (float*)d_out;
  float* attn  = (float*)d_out + 4194304;  // [B,H,512,1024] f32

  const dim3 blk(256);
  const dim3 blk5(512);

  // ---- 1: prep (cvt + all transposes + concats) ----
  {
    PrepP pp;
    pp.x = x; pp.enc = enc_o;
    pp.wsrc[0] = a1_wq; pp.wsrc[1] = a1_wk; pp.wsrc[2] = a1_wv; pp.wsrc[3] = a1_wo;
    pp.wsrc[4] = a2_wq; pp.wsrc[5] = a2_wk; pp.wsrc[6] = a2_wv; pp.wsrc[7] = a2_wo;
    pp.wsrc[8] = ff_w1; pp.wsrc[9] = ff_w2;
    pp.b0 = a1_bq; pp.b1 = a1_bk; pp.b2 = a1_bv; pp.b4 = a2_bk; pp.b5 = a2_bv;
    pp.xb = xb; pp.encb = encb; pp.wT = wT; pp.bqkv = bqkv; pp.bkv = bkv;
    prep_k<<<28692, blk, 0, stream>>>(pp);
  }

  // ---- 2: self-QKV [4096,3072] + cross-KV [8192,2048] in one launch ----
  {
    Gemm2P q;
    q.a = mkp(xb, wT, QKV, bqkv, nullptr, 0.f, 4096, 3072, 1024, 1024, 1024, 3072, 0,0,0,0,0,0);
    q.b = mkp(encb, wT + 5 * M1, KVc, bkv, nullptr, 0.f, 8192, 2048, 1024, 1024, 1024, 2048, 0,0,0,0,0,0);
    q.nA = 768; q.axw = 24; q.bxw = 16;
    gemm2_k<<<1792, blk, 0, stream>>>(q);
  }
  bf16* Qs = QKV;           // ld 3072
  bf16* Ks = QKV + 1024;
  bf16* Vs = QKV + 2048;
  bf16* Kc = KVc;           // ld 2048
  bf16* Vc = KVc + 1024;

  // ---- 3: both V transposes ----
  {
    Vt2P vp; vp.vs = Vs; vp.vc = Vc; vp.vts = VtS; vp.vtc = VtC;
    vt2_k<<<12288, blk, 0, stream>>>(vp);
  }

  // ---- 4: fused self attention ----
  {
    AttnP ap;
    ap.Q = Qs; ap.K = Ks; ap.Vt = VtS; ap.Pout = nullptr; ap.O = Ob; ap.kmask = nullptr;
    ap.ldq = 3072; ap.ldk = 3072; ap.ldv = 512;
    ap.sQb = 1572864; ap.sQh = 64; ap.sKb = 1572864; ap.sKh = 64;
    ap.sVb = 524288;  ap.sVh = 32768; ap.sPb = 0; ap.sPh = 0;
    ap.sOb = 524288;  ap.sOh = 64;
    attn_fused_k<512, true, false><<<dim3(1024), blk5, 0, stream>>>(ap);
  }

  // ---- 5: O-proj self, split-K=2 -> part[0..2) ----
  gemm_k<EPI_PART_F32><<<dim3(8, 32, 2), blk, 0, stream>>>(
      mkp(Ob, wT + 3 * M1, part, nullptr, nullptr, 0.f, 4096, 1024, 512, 1024, 1024, 1024,
          0, 512, 0, 512, 0, 4194304));

  // ---- 6: LN1 = LN(x + p0 + p1 + bo) ----
  ln_fuse_k<2><<<1024, blk, 0, stream>>>(x, part, 4194304, a1_bo, ln1_g, ln1_b, x1f, xcb);

  // ---- 7: cross Q ----
  gemm_k<EPI_BIAS_BF16><<<dim3(8, 32, 1), blk, 0, stream>>>(
      mkp(xcb, wT + 4 * M1, QKV, a2_bq, nullptr, 0.f, 4096, 1024, 1024, 1024, 1024, 1024, 0,0,0,0,0,0));
  bf16* Qc = QKV;          // ld 1024

  // ---- 8: fused cross attention (P f32 -> attn output) ----
  {
    AttnP ap;
    ap.Q = Qc; ap.K = Kc; ap.Vt = VtC; ap.Pout = attn; ap.O = Ob; ap.kmask = enc_mask;
    ap.ldq = 1024; ap.ldk = 2048; ap.ldv = 1024;
    ap.sQb = 524288;  ap.sQh = 64; ap.sKb = 2097152; ap.sKh = 64;
    ap.sVb = 1048576; ap.sVh = 65536; ap.sPb = 8388608; ap.sPh = 524288;
    ap.sOb = 524288;  ap.sOh = 64;
    attn_fused_k<1024, false, true><<<dim3(1024), blk5, 0, stream>>>(ap);
  }

  // ---- 9: O-proj cross, split-K=2 ----
  gemm_k<EPI_PART_F32><<<dim3(8, 32, 2), blk, 0, stream>>>(
      mkp(Ob, wT + 7 * M1, part, nullptr, nullptr, 0.f, 4096, 1024, 512, 1024, 1024, 1024,
          0, 512, 0, 512, 0, 4194304));

  // ---- 10: LN2 ----
  ln_fuse_k<2><<<1024, blk, 0, stream>>>(x1f, part, 4194304, a2_bo, ln2_g, ln2_b, x2f, xcb);

  // ---- 11: FFN1 (bias+ReLU, bf16) ----
  gemm_k<EPI_BIAS_RELU_BF16><<<dim3(32, 32, 1), blk, 0, stream>>>(
      mkp(xcb, wT + 8 * M1, Asf, ff_b1, nullptr, 0.f, 4096, 4096, 1024, 1024, 1024, 4096, 0,0,0,0,0,0));

  // ---- 12: FFN2 split-K=4 -> part[0..4) ----
  gemm_k<EPI_PART_F32><<<dim3(8, 32, 4), blk, 0, stream>>>(
      mkp(Asf, wT + 12 * M1, part, nullptr, nullptr, 0.f, 4096, 1024, 1024, 4096, 4096, 1024,
          0, 1024, 0, 1024, 0, 4194304));

  // ---- 13: LN3 = LN(x2f + 4 partials + ff_b2) -> out ----
  ln_fuse_k<4><<<1024, blk, 0, stream>>>(x2f, part, 4194304, ff_b2, ln3_g, ln3_b, out_x, nullptr);
}

// Round 6
// 953.943 us; speedup vs baseline: 1.0359x; 1.0359x over previous
//
#include <hip/hip_runtime.h>
#include <hip/hip_bf16.h>

// TransformerDecLayer on MI355X (gfx950).
// B=8, SQ=512, SK=1024, D=1024, H=16, DK=64, F=4096.
// GEMMs: bf16 MFMA 16x16x32, 128x128 tile, global_load_lds(16B) staging (m97 pattern).
// R4: launch-count 34 -> 13 (prep megakernel, co-launches, split-K + LN-fused reduce).
// R5: XCD swizzle for attention (K/V L2-resident per XCD: FETCH 135->21MB).
// R7: attention v5 — NO LDS staging of K/V (they're L2-resident via XCD swizzle);
//     K/V fragments loaded directly global->reg with 1-deep software pipeline.
//     LDS holds only S (self 64KB = 2 blk/CU, cross 128KB). Exactly TWO
//     __syncthreads() per block; zero vmcnt asm. Waves run free -> latency overlap.
// Workspace (MB): 0 xb(8) | 8 encb(16) | 24 x1f(16) | 40 x2f(16) | 56 xcb(8)
//   64 wT(32) | 96 biases(1) | 104 QKV/Qc(24) | 128 KVc(32) | 160 VtSelf(8)
//   176 Ob(8) | 200 part(64) | 264 Asf(32, FFN hidden) | 332 VtCross(16)

using bf16 = __hip_bfloat16;
typedef __attribute__((ext_vector_type(8))) short short8;
typedef __attribute__((ext_vector_type(4))) float f32x4;

#define DEVINL __device__ __forceinline__

DEVINL unsigned short bf16bits(float f) {
  __hip_bfloat16 h = __float2bfloat16(f);
  return *reinterpret_cast<unsigned short*>(&h);
}
DEVINL float bits2f(unsigned short u) {
  return __uint_as_float(((unsigned int)u) << 16);
}
DEVINL float tofloat(float f) { return f; }
DEVINL float tofloat(bf16 h) { return __bfloat162float(h); }

#define GLD16(gp, lp) __builtin_amdgcn_global_load_lds( \
    (__attribute__((address_space(1))) const void*)(gp), \
    (__attribute__((address_space(3))) void*)(lp), 16, 0, 0)

struct GemmP {
  const bf16* A; const bf16* Bt; void* C;
  const float* bias; const int* kmask;
  float scale;
  int M, N, K, lda, ldb, ldc;
  long sAb, sAh, sBb, sBh, sCb, sCh;  // element strides: base = (z>>4)*sXb + (z&15)*sXh
};

enum { EPI_BIAS_BF16 = 0, EPI_CAUSAL_BF16, EPI_KMASK_F32, EPI_NONE_BF16,
       EPI_BIAS_F32, EPI_BIAS_RELU_BF16, EPI_PART_F32 };

template<int EPI>
DEVINL void gemm_body(const GemmP& p, int bx, int by, int bz) {
  __shared__ bf16 As[128 * 32];
  __shared__ bf16 Bs[128 * 32];
  const int t = threadIdx.x;
  const int lane = t & 63;
  const int w = t >> 6;
  const int zb = bz >> 4, zh = bz & 15;
  const int m0 = by * 128, n0 = bx * 128;

  const bf16* Ab = p.A + (long)zb * p.sAb + (long)zh * p.sAh;
  const bf16* Bb = p.Bt + (long)zb * p.sBb + (long)zh * p.sBh;
  const int fl = lane & 15, fq = lane >> 4;
  const int wm = (w >> 1) * 64, wn = (w & 1) * 64;

  f32x4 acc[4][4];
#pragma unroll
  for (int i = 0; i < 4; ++i)
#pragma unroll
    for (int j = 0; j < 4; ++j) acc[i][j] = (f32x4){0.f, 0.f, 0.f, 0.f};

  const int sr = t >> 2;          // staging row 0..63
  const int sc = (t & 3) * 8;     // staging col (bf16 elems)
  char* ldsA = (char*)As + w * 1024;
  char* ldsB = (char*)Bs + w * 1024;

  int brow0 = n0 + sr;      if (brow0 > p.N - 1) brow0 = p.N - 1;
  int brow1 = n0 + sr + 64; if (brow1 > p.N - 1) brow1 = p.N - 1;

  for (int k0 = 0; k0 < p.K; k0 += 32) {
    GLD16(Ab + (long)(m0 + sr) * p.lda + k0 + sc, ldsA);
    GLD16(Ab + (long)(m0 + sr + 64) * p.lda + k0 + sc, ldsA + 4096);
    GLD16(Bb + (long)brow0 * p.ldb + k0 + sc, ldsB);
    GLD16(Bb + (long)brow1 * p.ldb + k0 + sc, ldsB + 4096);
    __syncthreads();

    short8 af[4], bfv[4];
#pragma unroll
    for (int i = 0; i < 4; ++i)
      af[i] = *(const short8*)(As + (wm + i * 16 + fl) * 32 + fq * 8);
#pragma unroll
    for (int j = 0; j < 4; ++j)
      bfv[j] = *(const short8*)(Bs + (wn + j * 16 + fl) * 32 + fq * 8);
#pragma unroll
    for (int i = 0; i < 4; ++i)
#pragma unroll
      for (int j = 0; j < 4; ++j)
        acc[i][j] = __builtin_amdgcn_mfma_f32_16x16x32_bf16(af[i], bfv[j], acc[i][j], 0, 0, 0);
    __syncthreads();
  }

  const float NEGINF = -__builtin_inff();
  const long cbase = (long)zb * p.sCb + (long)zh * p.sCh;
#pragma unroll
  for (int i = 0; i < 4; ++i) {
#pragma unroll
    for (int j = 0; j < 4; ++j) {
#pragma unroll
      for (int r = 0; r < 4; ++r) {
        int row = m0 + wm + i * 16 + fq * 4 + r;
        int col = n0 + wn + j * 16 + fl;
        if (col < p.N) {
          float v = acc[i][j][r];
          if (EPI == EPI_BIAS_BF16 || EPI == EPI_BIAS_F32 || EPI == EPI_BIAS_RELU_BF16)
            v += p.bias[col];
          if (EPI == EPI_BIAS_RELU_BF16) v = v > 0.f ? v : 0.f;
          if (EPI == EPI_CAUSAL_BF16) { v *= p.scale; if (col > row) v = NEGINF; }
          if (EPI == EPI_KMASK_F32)   { v *= p.scale; if (p.kmask[zb * 1024 + col] == 0) v = NEGINF; }
          long off = cbase + (long)row * p.ldc + col;
          if (EPI == EPI_KMASK_F32 || EPI == EPI_BIAS_F32 || EPI == EPI_PART_F32)
            ((float*)p.C)[off] = v;
          else ((bf16*)p.C)[off] = __float2bfloat16(v);
        }
      }
    }
  }
}

template<int EPI>
__global__ __launch_bounds__(256)
void gemm_k(GemmP p) {
  gemm_body<EPI>(p, blockIdx.x, blockIdx.y, blockIdx.z);
}

// two independent EPI_BIAS_BF16 gemms in one launch (linear block decode)
struct Gemm2P { GemmP a, b; int nA, axw, bxw; };
__global__ __launch_bounds__(256)
void gemm2_k(Gemm2P q) {
  const int b = blockIdx.x;
  if (b < q.nA) gemm_body<EPI_BIAS_BF16>(q.a, b % q.axw, b / q.axw, 0);
  else { const int c = b - q.nA; gemm_body<EPI_BIAS_BF16>(q.b, c % q.bxw, c / q.bxw, 0); }
}

// ---------------- fused attention v5 (register-direct K/V, S-only LDS) ----------------
// One block = 64 q-rows of one (b,h). 8 waves (512 threads).
// Wave w: q-half qh=(w>>2)*32 rows, kv/dk col-quarter wc=(w&3)*16.
// S[64][SK] bf16 in LDS, byte-swizzled (^(row&7)<<4). K and V^T fragments are read
// DIRECTLY from global (L2-resident via XCD swizzle) with a 1-deep reg pipeline —
// no LDS staging, no vmcnt asm, only two __syncthreads() per block.
struct AttnP {
  const bf16 *Q, *K, *Vt;
  float* Pout; bf16* O;
  const int* kmask;
  int ldq, ldk, ldv;
  long sQb, sQh, sKb, sKh, sVb, sVh, sPb, sPh, sOb, sOh;
};

template<int SK, bool CAUSAL, bool WRITE_P>
__global__ __launch_bounds__(512)
void attn_fused_k(AttnP p) {
  constexpr int TKMAX = SK / 64;
  __shared__ bf16 S[64 * SK];        // swizzled bf16 scores -> probs
  const int t = threadIdx.x;
  const int lane = t & 63;
  const int w = t >> 6;              // 0..7
  const int fl = lane & 15, fq = lane >> 4;
  const int qh = w >> 2;             // q 32-row half
  const int wc = w & 3;              // 16-col quarter
  // bijective XCD swizzle over 1024 blocks: XCD gets 128 consecutive wg
  // = 16 (b,h) x 8 q-blocks -> K/V stays in that XCD's L2.
  const int lin = blockIdx.x;
  const int wg = (lin & 7) * 128 + (lin >> 3);
  const int by = wg & 7;
  const int z = wg >> 3;
  const int zb = z >> 4, zh = z & 15;
  const int q0 = by * 64;
  const float NEGINF = -__builtin_inff();

  const bf16* Qb = p.Q + (long)zb * p.sQb + (long)zh * p.sQh;
  const bf16* Kb = p.K + (long)zb * p.sKb + (long)zh * p.sKh;
  const bf16* Vb = p.Vt + (long)zb * p.sVb + (long)zh * p.sVh;

  const int Tk = CAUSAL ? (q0 >> 6) + 1 : TKMAX;   // causal: only tiles touching diag

  // Q fragments (regs, L2-resident)
  short8 af[2][2];
#pragma unroll
  for (int i = 0; i < 2; ++i)
#pragma unroll
    for (int kk = 0; kk < 2; ++kk)
      af[i][kk] = *(const short8*)(Qb + (long)(q0 + qh * 32 + i * 16 + fl) * p.ldq + kk * 32 + fq * 8);

  int kmv[CAUSAL ? 1 : TKMAX];
  if (!CAUSAL) {
#pragma unroll
    for (int kt = 0; kt < TKMAX; ++kt)
      kmv[kt] = p.kmask[zb * 1024 + kt * 64 + wc * 16 + fl];
  }

  // ---- phase 1: S = Q K^T * scale (+mask), bf16 into LDS ----
  // K B-fragment direct from global: lane (fq,fl) reads K[kvrow=kt*64+wc*16+fl][dk kk*32+fq*8 ..+8]
  const bf16* kbase = Kb + (long)(wc * 16 + fl) * p.ldk + fq * 8;
  const long kstep = (long)64 * p.ldk;
  short8 kcur[2];
  kcur[0] = *(const short8*)(kbase);
  kcur[1] = *(const short8*)(kbase + 32);
  for (int kt = 0; kt < Tk; ++kt) {
    short8 knxt[2];
    if (kt + 1 < Tk) {
      const bf16* kp = kbase + (long)(kt + 1) * kstep;
      knxt[0] = *(const short8*)(kp);
      knxt[1] = *(const short8*)(kp + 32);
    }
    f32x4 acc[2] = {(f32x4){0.f,0.f,0.f,0.f}, (f32x4){0.f,0.f,0.f,0.f}};
#pragma unroll
    for (int kk = 0; kk < 2; ++kk) {
      acc[0] = __builtin_amdgcn_mfma_f32_16x16x32_bf16(af[0][kk], kcur[kk], acc[0], 0, 0, 0);
      acc[1] = __builtin_amdgcn_mfma_f32_16x16x32_bf16(af[1][kk], kcur[kk], acc[1], 0, 0, 0);
    }
    const int col = kt * 64 + wc * 16 + fl;
    const bool mok = CAUSAL || (kmv[CAUSAL ? 0 : kt] != 0);
#pragma unroll
    for (int i = 0; i < 2; ++i) {
#pragma unroll
      for (int r = 0; r < 4; ++r) {
        int row = qh * 32 + i * 16 + fq * 4 + r;
        float v = acc[i][r] * 0.125f;
        if (CAUSAL) { if (col > q0 + row) v = NEGINF; }
        else if (!mok) v = NEGINF;
        *(bf16*)((char*)S + (((row * SK + col) * 2) ^ ((row & 7) << 4))) = __float2bfloat16(v);
      }
    }
    kcur[0] = knxt[0]; kcur[1] = knxt[1];
  }
  __syncthreads();

  // ---- phase 2: softmax (wave w owns rows w*8..w*8+7); bf16 P to LDS, f32 P out ----
  float* Pf = WRITE_P ? (p.Pout + (long)zb * p.sPb + (long)zh * p.sPh) : nullptr;
  constexpr int NC = SK / 512;
  const int lim = Tk * 64;
  for (int rr = 0; rr < 8; ++rr) {
    const int row = w * 8 + rr;
    const int rg = q0 + row;
    const int swz = (row & 7) << 4;
    float fv[NC][8];
#pragma unroll
    for (int c = 0; c < NC; ++c) {
      const int col = c * 512 + lane * 8;
      if (!CAUSAL || col < lim) {
        short8 sv = *(const short8*)((char*)S + (((row * SK + col) * 2) ^ swz));
#pragma unroll
        for (int j = 0; j < 8; ++j) fv[c][j] = bits2f((unsigned short)sv[j]);
      } else {
#pragma unroll
        for (int j = 0; j < 8; ++j) fv[c][j] = NEGINF;
      }
    }
    float mx = fv[0][0];
#pragma unroll
    for (int c = 0; c < NC; ++c)
#pragma unroll
      for (int j = 0; j < 8; ++j) mx = fmaxf(mx, fv[c][j]);
    for (int off = 32; off; off >>= 1) mx = fmaxf(mx, __shfl_xor(mx, off, 64));
    float s = 0.f;
#pragma unroll
    for (int c = 0; c < NC; ++c)
#pragma unroll
      for (int j = 0; j < 8; ++j) { fv[c][j] = expf(fv[c][j] - mx); s += fv[c][j]; }
    for (int off = 32; off; off >>= 1) s += __shfl_xor(s, off, 64);
    const float inv = 1.f / s;
#pragma unroll
    for (int c = 0; c < NC; ++c) {
      const int col = c * 512 + lane * 8;
      if (!CAUSAL || col < lim) {
        short8 o;
#pragma unroll
        for (int j = 0; j < 8; ++j) o[j] = (short)bf16bits(fv[c][j] * inv);
        *(short8*)((char*)S + (((row * SK + col) * 2) ^ swz)) = o;
        if (WRITE_P) {
          float* pp = Pf + (long)rg * SK + col;
          f32x4 o0, o1;
#pragma unroll
          for (int j = 0; j < 4; ++j) { o0[j] = fv[c][j] * inv; o1[j] = fv[c][4 + j] * inv; }
          *(f32x4*)pp = o0;
          *(f32x4*)(pp + 4) = o1;
        }
      }
    }
  }
  __syncthreads();

  // ---- phase 3: O = P V ; wave w: q-half qh, dk cols wc*16..+15 ----
  // V^T B-fragment direct from global: lane (fq,fl) reads Vt[dk=wc*16+fl][sk vt*64+kk*32+fq*8]
  const bf16* vbase = Vb + (long)(wc * 16 + fl) * p.ldv + fq * 8;
  f32x4 ao[2] = {(f32x4){0.f,0.f,0.f,0.f}, (f32x4){0.f,0.f,0.f,0.f}};
  short8 vcur[2];
  vcur[0] = *(const short8*)(vbase);
  vcur[1] = *(const short8*)(vbase + 32);
  for (int vt = 0; vt < Tk; ++vt) {
    short8 vnxt[2];
    if (vt + 1 < Tk) {
      const bf16* vp = vbase + (vt + 1) * 64;
      vnxt[0] = *(const short8*)(vp);
      vnxt[1] = *(const short8*)(vp + 32);
    }
#pragma unroll
    for (int i = 0; i < 2; ++i) {
      const int row = qh * 32 + i * 16 + fl;
#pragma unroll
      for (int kk = 0; kk < 2; ++kk) {
        const int col = vt * 64 + kk * 32 + fq * 8;
        short8 pa = *(const short8*)((char*)S + (((row * SK + col) * 2) ^ ((row & 7) << 4)));
        ao[i] = __builtin_amdgcn_mfma_f32_16x16x32_bf16(pa, vcur[kk], ao[i], 0, 0, 0);
      }
    }
    vcur[0] = vnxt[0]; vcur[1] = vnxt[1];
  }

  bf16* Ob_ = p.O + (long)zb * p.sOb + (long)zh * p.sOh;
#pragma unroll
  for (int i = 0; i < 2; ++i)
#pragma unroll
    for (int r = 0; r < 4; ++r) {
      int row = q0 + qh * 32 + i * 16 + fq * 4 + r;
      Ob_[(long)row * 1024 + wc * 16 + fl] = __float2bfloat16(ao[i][r]);
    }
}

// out = LN(x + sum_{s<NP} part[s] + pbias); writes f32 outf and optional bf16 outb.
template<int NP>
__global__ __launch_bounds__(256)
void ln_fuse_k(const float* __restrict__ x, const float* __restrict__ part, long pstride,
               const float* __restrict__ pb,
               const float* __restrict__ g, const float* __restrict__ bt,
               float* __restrict__ outf, bf16* __restrict__ outb) {
  const int lane = threadIdx.x & 63;
  const long row = (long)blockIdx.x * 4 + (threadIdx.x >> 6);
  const float* px = x + row * 1024;
  float4 v[4];
  float s = 0.f;
#pragma unroll
  for (int c = 0; c < 4; ++c) {
    const int col = c * 256 + lane * 4;
    float4 a = *(const float4*)(px + col);
    float4 bb = *(const float4*)(pb + col);
    v[c].x = a.x + bb.x; v[c].y = a.y + bb.y; v[c].z = a.z + bb.z; v[c].w = a.w + bb.w;
#pragma unroll
    for (int sl = 0; sl < NP; ++sl) {
      float4 pp = *(const float4*)(part + sl * pstride + row * 1024 + col);
      v[c].x += pp.x; v[c].y += pp.y; v[c].z += pp.z; v[c].w += pp.w;
    }
    s += v[c].x + v[c].y + v[c].z + v[c].w;
  }
  for (int off = 32; off; off >>= 1) s += __shfl_xor(s, off, 64);
  float mu = s * (1.f / 1024.f);
  float q = 0.f;
#pragma unroll
  for (int c = 0; c < 4; ++c) {
    float dx = v[c].x - mu, dy = v[c].y - mu, dz = v[c].z - mu, dw = v[c].w - mu;
    q += dx * dx + dy * dy + dz * dz + dw * dw;
  }
  for (int off = 32; off; off >>= 1) q += __shfl_xor(q, off, 64);
  float rs = rsqrtf(q * (1.f / 1024.f) + 1e-5f);
#pragma unroll
  for (int c = 0; c < 4; ++c) {
    int col = c * 256 + lane * 4;
    float4 gg = *(const float4*)(g + col);
    float4 bb = *(const float4*)(bt + col);
    float4 o;
    o.x = (v[c].x - mu) * rs * gg.x + bb.x;
    o.y = (v[c].y - mu) * rs * gg.y + bb.y;
    o.z = (v[c].z - mu) * rs * gg.z + bb.z;
    o.w = (v[c].w - mu) * rs * gg.w + bb.w;
    *(float4*)(outf + row * 1024 + col) = o;
    if (outb) {
      uint2 pk;
      pk.x = bf16bits(o.x) | ((unsigned)bf16bits(o.y) << 16);
      pk.y = bf16bits(o.z) | ((unsigned)bf16bits(o.w) << 16);
      *(uint2*)(outb + row * 1024 + col) = pk;
    }
  }
}

// 32x32 transpose tile body (out[c*ldo+r] = bf16(in[r*ldi+c]))
template<typename TI>
DEVINL void tr_body(const TI* __restrict__ pin, bf16* __restrict__ pout,
                    int ldi, int ldo, int c0, int r0, int t, float tile[32][33]) {
  const int tx = t & 31, ty = t >> 5;  // 32x8
#pragma unroll
  for (int i = 0; i < 32; i += 8)
    tile[ty + i][tx] = tofloat(pin[(long)(r0 + ty + i) * ldi + c0 + tx]);
  __syncthreads();
#pragma unroll
  for (int i = 0; i < 32; i += 8)
    pout[(long)(c0 + ty + i) * ldo + r0 + tx] = __float2bfloat16(tile[tx][ty + i]);
}

// prep megakernel: cvt x, cvt enc, 8 square weight^T, ff_w1^T, ff_w2^T, bias concats.
struct PrepP {
  const float *x, *enc;
  const float* wsrc[10];
  const float *b0, *b1, *b2, *b4, *b5;
  bf16 *xb, *encb, *wT;
  float *bqkv, *bkv;
};
__global__ __launch_bounds__(256)
void prep_k(PrepP p) {
  __shared__ float tile[32][33];
  const int b = blockIdx.x, t = threadIdx.x;
  if (b < 12288) {
    const float* src = (b < 4096) ? p.x : p.enc;
    bf16* dst = (b < 4096) ? p.xb : p.encb;
    long i = (long)(b < 4096 ? b : b - 4096) * 256 + t;
    float4 v = *(const float4*)(src + i * 4);
    uint2 pk;
    pk.x = bf16bits(v.x) | ((unsigned)bf16bits(v.y) << 16);
    pk.y = bf16bits(v.z) | ((unsigned)bf16bits(v.w) << 16);
    *(uint2*)(dst + i * 4) = pk;
  } else if (b < 20480) {
    int l = b - 12288; int wdx = l >> 10; l &= 1023;
    tr_body<float>(p.wsrc[wdx], p.wT + (long)wdx * 1048576, 1024, 1024,
                   (l & 31) * 32, (l >> 5) * 32, t, tile);
  } else if (b < 24576) {
    int l = b - 20480;   // ff_w1 [1024][4096] -> [4096][1024]
    tr_body<float>(p.wsrc[8], p.wT + 8l * 1048576, 4096, 1024,
                   (l & 127) * 32, (l >> 7) * 32, t, tile);
  } else if (b < 28672) {
    int l = b - 24576;   // ff_w2 [4096][1024] -> [1024][4096]
    tr_body<float>(p.wsrc[9], p.wT + 12l * 1048576, 1024, 4096,
                   (l % 32) * 32, (l / 32) * 32, t, tile);
  } else if (b < 28684) {
    int i = (b - 28672) * 256 + t;
    p.bqkv[i] = (i < 1024) ? p.b0[i] : (i < 2048 ? p.b1[i - 1024] : p.b2[i - 2048]);
  } else {
    int i = (b - 28684) * 256 + t;
    p.bkv[i] = (i < 1024) ? p.b4[i] : p.b5[i - 1024];
  }
}

// both V transposes in one launch. [0,4096): self (z=128, 2x16 tiles); rest: cross (2x32).
struct Vt2P { const bf16 *vs, *vc; bf16 *vts, *vtc; };
__global__ __launch_bounds__(256)
void vt2_k(Vt2P p) {
  __shared__ float tile[32][33];
  const int b = blockIdx.x, t = threadIdx.x;
  if (b < 4096) {
    int z = b >> 5, l = b & 31;
    int zb = z >> 4, zh = z & 15;
    tr_body<bf16>(p.vs + (long)zb * 1572864 + zh * 64,
                  p.vts + (long)zb * 524288 + zh * 32768,
                  3072, 512, (l & 1) * 32, (l >> 1) * 32, t, tile);
  } else {
    int c = b - 4096;
    int z = c >> 6, l = c & 63;
    int zb = z >> 4, zh = z & 15;
    tr_body<bf16>(p.vc + (long)zb * 2097152 + zh * 64,
                  p.vtc + (long)zb * 1048576 + zh * 65536,
                  2048, 1024, (l & 1) * 32, (l >> 1) * 32, t, tile);
  }
}

static inline GemmP mkp(const void* A, const bf16* Bt, void* C,
                        const float* bias, const int* km, float sc,
                        int M, int N, int K, int lda, int ldb, int ldc,
                        long sAb, long sAh, long sBb, long sBh, long sCb, long sCh) {
  GemmP p;
  p.A = (const bf16*)A; p.Bt = Bt; p.C = C; p.bias = bias; p.kmask = km; p.scale = sc;
  p.M = M; p.N = N; p.K = K; p.lda = lda; p.ldb = ldb; p.ldc = ldc;
  p.sAb = sAb; p.sAh = sAh; p.sBb = sBb; p.sBh = sBh; p.sCb = sCb; p.sCh = sCh;
  return p;
}

extern "C" void kernel_launch(void* const* d_in, const int* in_sizes, int n_in,
                              void* d_out, int out_size, void* d_ws, size_t ws_size,
                              hipStream_t stream) {
  const float* x        = (const float*)d_in[0];
  const float* enc_o    = (const float*)d_in[1];
  const int*   enc_mask = (const int*)d_in[2];
  const float* a1_wq = (const float*)d_in[3];  const float* a1_bq = (const float*)d_in[4];
  const float* a1_wk = (const float*)d_in[5];  const float* a1_bk = (const float*)d_in[6];
  const float* a1_wv = (const float*)d_in[7];  const float* a1_bv = (const float*)d_in[8];
  const float* a1_wo = (const float*)d_in[9];  const float* a1_bo = (const float*)d_in[10];
  const float* a2_wq = (const float*)d_in[11]; const float* a2_bq = (const float*)d_in[12];
  const float* a2_wk = (const float*)d_in[13]; const float* a2_bk = (const float*)d_in[14];
  const float* a2_wv = (const float*)d_in[15]; const float* a2_bv = (const float*)d_in[16];
  const float* a2_wo = (const float*)d_in[17]; const float* a2_bo = (const float*)d_in[18];
  const float* ff_w1 = (const float*)d_in[19]; const float* ff_b1 = (const float*)d_in[20];
  const float* ff_w2 = (const float*)d_in[21]; const float* ff_b2 = (const float*)d_in[22];
  const float* ln1_g = (const float*)d_in[23]; const float* ln1_b = (const float*)d_in[24];
  const float* ln2_g = (const float*)d_in[25]; const float* ln2_b = (const float*)d_in[26];
  const float* ln3_g = (const float*)d_in[27]; const float* ln3_b = (const float*)d_in[28];

  const size_t MB = 1u << 20;
  const long M1 = 1048576;  // elements
  char* w = (char*)d_ws;
  bf16*  xb   = (bf16*)(w + 0);
  bf16*  encb = (bf16*)(w + 8 * MB);
  float* x1f  = (float*)(w + 24 * MB);
  float* x2f  = (float*)(w + 40 * MB);
  bf16*  xcb  = (bf16*)(w + 56 * MB);
  bf16*  wT   = (bf16*)(w + 64 * MB);   // 16M elems = 32MB
  float* bqkv = (float*)(w + 96 * MB);  // [3072]
  float* bkv  = (float*)(w + 96 * MB + 16384);  // [2048]
  bf16*  QKV  = (bf16*)(w + 104 * MB);  // self: [4096,3072]; cross: Qc [4096,1024]
  bf16*  KVc  = (bf16*)(w + 128 * MB);  // cross: [8192,2048]
  bf16*  VtS  = (bf16*)(w + 160 * MB);  // self V^T [B,H,64,512] 8MB
  bf16*  Ob   = (bf16*)(w + 176 * MB);
  float* part = (float*)(w + 200 * MB); // 4 x [4096,1024] f32
  bf16*  Asf  = (bf16*)(w + 264 * MB);  // FFN hidden 32MB
  bf16*  VtC  = (bf16*)(w + 332 * MB);  // cross V^T [B,H,64,1024] 16MB

  float* out_x = (float*)d_out;
  float* attn  = (float*)d_out + 4194304;  // [B,H,512,1024] f32

  const dim3 blk(256);
  const dim3 blk5(512);

  // ---- 1: prep (cvt + all transposes + concats) ----
  {
    PrepP pp;
    pp.x = x; pp.enc = enc_o;
    pp.wsrc[0] = a1_wq; pp.wsrc[1] = a1_wk; pp.wsrc[2] = a1_wv; pp.wsrc[3] = a1_wo;
    pp.wsrc[4] = a2_wq; pp.wsrc[5] = a2_wk; pp.wsrc[6] = a2_wv; pp.wsrc[7] = a2_wo;
    pp.wsrc[8] = ff_w1; pp.wsrc[9] = ff_w2;
    pp.b0 = a1_bq; pp.b1 = a1_bk; pp.b2 = a1_bv; pp.b4 = a2_bk; pp.b5 = a2_bv;
    pp.xb = xb; pp.encb = encb; pp.wT = wT; pp.bqkv = bqkv; pp.bkv = bkv;
    prep_k<<<28692, blk, 0, stream>>>(pp);
  }

  // ---- 2: self-QKV [4096,3072] + cross-KV [8192,2048] in one launch ----
  {
    Gemm2P q;
    q.a = mkp(xb, wT, QKV, bqkv, nullptr, 0.f, 4096, 3072, 1024, 1024, 1024, 3072, 0,0,0,0,0,0);
    q.b = mkp(encb, wT + 5 * M1, KVc, bkv, nullptr, 0.f, 8192, 2048, 1024, 1024, 1024, 2048, 0,0,0,0,0,0);
    q.nA = 768; q.axw = 24; q.bxw = 16;
    gemm2_k<<<1792, blk, 0, stream>>>(q);
  }
  bf16* Qs = QKV;           // ld 3072
  bf16* Ks = QKV + 1024;
  bf16* Vs = QKV + 2048;
  bf16* Kc = KVc;           // ld 2048
  bf16* Vc = KVc + 1024;

  // ---- 3: both V transposes ----
  {
    Vt2P vp; vp.vs = Vs; vp.vc = Vc; vp.vts = VtS; vp.vtc = VtC;
    vt2_k<<<12288, blk, 0, stream>>>(vp);
  }

  // ---- 4: fused self attention ----
  {
    AttnP ap;
    ap.Q = Qs; ap.K = Ks; ap.Vt = VtS; ap.Pout = nullptr; ap.O = Ob; ap.kmask = nullptr;
    ap.ldq = 3072; ap.ldk = 3072; ap.ldv = 512;
    ap.sQb = 1572864; ap.sQh = 64; ap.sKb = 1572864; ap.sKh = 64;
    ap.sVb = 524288;  ap.sVh = 32768; ap.sPb = 0; ap.sPh = 0;
    ap.sOb = 524288;  ap.sOh = 64;
    attn_fused_k<512, true, false><<<dim3(1024), blk5, 0, stream>>>(ap);
  }

  // ---- 5: O-proj self, split-K=2 -> part[0..2) ----
  gemm_k<EPI_PART_F32><<<dim3(8, 32, 2), blk, 0, stream>>>(
      mkp(Ob, wT + 3 * M1, part, nullptr, nullptr, 0.f, 4096, 1024, 512, 1024, 1024, 1024,
          0, 512, 0, 512, 0, 4194304));

  // ---- 6: LN1 = LN(x + p0 + p1 + bo) ----
  ln_fuse_k<2><<<1024, blk, 0, stream>>>(x, part, 4194304, a1_bo, ln1_g, ln1_b, x1f, xcb);

  // ---- 7: cross Q ----
  gemm_k<EPI_BIAS_BF16><<<dim3(8, 32, 1), blk, 0, stream>>>(
      mkp(xcb, wT + 4 * M1, QKV, a2_bq, nullptr, 0.f, 4096, 1024, 1024, 1024, 1024, 1024, 0,0,0,0,0,0));
  bf16* Qc = QKV;          // ld 1024

  // ---- 8: fused cross attention (P f32 -> attn output) ----
  {
    AttnP ap;
    ap.Q = Qc; ap.K = Kc; ap.Vt = VtC; ap.Pout = attn; ap.O = Ob; ap.kmask = enc_mask;
    ap.ldq = 1024; ap.ldk = 2048; ap.ldv = 1024;
    ap.sQb = 524288;  ap.sQh = 64; ap.sKb = 2097152; ap.sKh = 64;
    ap.sVb = 1048576; ap.sVh = 65536; ap.sPb = 8388608; ap.sPh = 524288;
    ap.sOb = 524288;  ap.sOh = 64;
    attn_fused_k<1024, false, true><<<dim3(1024), blk5, 0, stream>>>(ap);
  }

  // ---- 9: O-proj cross, split-K=2 ----
  gemm_k<EPI_PART_F32><<<dim3(8, 32, 2), blk, 0, stream>>>(
      mkp(Ob, wT + 7 * M1, part, nullptr, nullptr, 0.f, 4096, 1024, 512, 1024, 1024, 1024,
          0, 512, 0, 512, 0, 4194304));

  // ---- 10: LN2 ----
  ln_fuse_k<2><<<1024, blk, 0, stream>>>(x1f, part, 4194304, a2_bo, ln2_g, ln2_b, x2f, xcb);

  // ---- 11: FFN1 (bias+ReLU, bf16) ----
  gemm_k<EPI_BIAS_RELU_BF16><<<dim3(32, 32, 1), blk, 0, stream>>>(
      mkp(xcb, wT + 8 * M1, Asf, ff_b1, nullptr, 0.f, 4096, 4096, 1024, 1024, 1024, 4096, 0,0,0,0,0,0));

  // ---- 12: FFN2 split-K=4 -> part[0..4) ----
  gemm_k<EPI_PART_F32><<<dim3(8, 32, 4), blk, 0, stream>>>(
      mkp(Asf, wT + 12 * M1, part, nullptr, nullptr, 0.f, 4096, 1024, 1024, 4096, 4096, 1024,
          0, 1024, 0, 1024, 0, 4194304));

  // ---- 13: LN3 = LN(x2f + 4 partials + ff_b2) -> out ----
  ln_fuse_k<4><<<1024, blk, 0, stream>>>(x2f, part, 4194304, ff_b2, ln3_g, ln3_b, out_x, nullptr);
}